// Round 1
// baseline (6291.709 us; speedup 1.0000x reference)
//
#include <hip/hip_runtime.h>

#define NN 500000
#define NE 16000000

// ws layout (floats):
// [0,N)        deg -> dinv (in place)
// [N,2N)       s1   (layer1 scalar agg)
// [2N,6N)      g2   (h1 @ W2, 4 per node)
// [6N,10N)     agg2 (4 per node)
// [10N,12N)    g3   (h2 @ W3, 2 per node)
// [12N,14N)    agg3 (2 per node)

__global__ void init_ws(float* __restrict__ ws) {
    long long stride = (long long)gridDim.x * blockDim.x;
    for (long long i = (long long)blockIdx.x * blockDim.x + threadIdx.x;
         i < 14LL * NN; i += stride) {
        ws[i] = (i < NN) ? 1.0f : 0.0f;   // deg starts at 1 (self loop)
    }
}

__global__ void deg_kernel(const int* __restrict__ dst, float* __restrict__ deg) {
    int e = (blockIdx.x * blockDim.x + threadIdx.x) * 4;
    if (e + 3 < NE) {
        int4 d = *(const int4*)(dst + e);
        unsafeAtomicAdd(&deg[d.x], 1.0f);
        unsafeAtomicAdd(&deg[d.y], 1.0f);
        unsafeAtomicAdd(&deg[d.z], 1.0f);
        unsafeAtomicAdd(&deg[d.w], 1.0f);
    } else {
        for (; e < NE; ++e) unsafeAtomicAdd(&deg[dst[e]], 1.0f);
    }
}

__global__ void dinv_kernel(float* __restrict__ deg) {
    int i = blockIdx.x * blockDim.x + threadIdx.x;
    if (i < NN) deg[i] = rsqrtf(deg[i]);
}

__global__ void agg1_kernel(const int* __restrict__ src, const int* __restrict__ dst,
                            const float* __restrict__ x, const float* __restrict__ dinv,
                            float* __restrict__ s1) {
    int e = (blockIdx.x * blockDim.x + threadIdx.x) * 4;
    if (e + 3 < NE) {
        int4 s = *(const int4*)(src + e);
        int4 d = *(const int4*)(dst + e);
        unsafeAtomicAdd(&s1[d.x], x[s.x] * dinv[s.x] * dinv[d.x]);
        unsafeAtomicAdd(&s1[d.y], x[s.y] * dinv[s.y] * dinv[d.y]);
        unsafeAtomicAdd(&s1[d.z], x[s.z] * dinv[s.z] * dinv[d.z]);
        unsafeAtomicAdd(&s1[d.w], x[s.w] * dinv[s.w] * dinv[d.w]);
    } else {
        for (; e < NE; ++e)
            unsafeAtomicAdd(&s1[dst[e]], x[src[e]] * dinv[src[e]] * dinv[dst[e]]);
    }
}

__global__ void h1g2_kernel(const float* __restrict__ x, const float* __restrict__ dinv,
                            const float* __restrict__ s1,
                            const float* __restrict__ W1, const float* __restrict__ b1,
                            const float* __restrict__ W2,
                            float* __restrict__ g2) {
    int i = blockIdx.x * blockDim.x + threadIdx.x;
    if (i >= NN) return;
    float di = dinv[i];
    float t = s1[i] + x[i] * di * di;
    float h1[4];
#pragma unroll
    for (int f = 0; f < 4; ++f) h1[f] = tanhf(t * W1[f] + b1[f]);
    float4 g;
    g.x = h1[0]*W2[0] + h1[1]*W2[4] + h1[2]*W2[8]  + h1[3]*W2[12];
    g.y = h1[0]*W2[1] + h1[1]*W2[5] + h1[2]*W2[9]  + h1[3]*W2[13];
    g.z = h1[0]*W2[2] + h1[1]*W2[6] + h1[2]*W2[10] + h1[3]*W2[14];
    g.w = h1[0]*W2[3] + h1[1]*W2[7] + h1[2]*W2[11] + h1[3]*W2[15];
    ((float4*)g2)[i] = g;
}

__global__ void agg2_kernel(const int* __restrict__ src, const int* __restrict__ dst,
                            const float* __restrict__ g2, const float* __restrict__ dinv,
                            float* __restrict__ agg2) {
    int e = (blockIdx.x * blockDim.x + threadIdx.x) * 4;
    if (e + 3 < NE) {
        int4 s = *(const int4*)(src + e);
        int4 d = *(const int4*)(dst + e);
#pragma unroll
        for (int k = 0; k < 4; ++k) {
            int ss = (k==0)?s.x:(k==1)?s.y:(k==2)?s.z:s.w;
            int dd = (k==0)?d.x:(k==1)?d.y:(k==2)?d.z:d.w;
            float nrm = dinv[ss] * dinv[dd];
            float4 g = ((const float4*)g2)[ss];
            unsafeAtomicAdd(&agg2[dd*4+0], g.x * nrm);
            unsafeAtomicAdd(&agg2[dd*4+1], g.y * nrm);
            unsafeAtomicAdd(&agg2[dd*4+2], g.z * nrm);
            unsafeAtomicAdd(&agg2[dd*4+3], g.w * nrm);
        }
    } else {
        for (; e < NE; ++e) {
            int ss = src[e], dd = dst[e];
            float nrm = dinv[ss] * dinv[dd];
            float4 g = ((const float4*)g2)[ss];
            unsafeAtomicAdd(&agg2[dd*4+0], g.x * nrm);
            unsafeAtomicAdd(&agg2[dd*4+1], g.y * nrm);
            unsafeAtomicAdd(&agg2[dd*4+2], g.z * nrm);
            unsafeAtomicAdd(&agg2[dd*4+3], g.w * nrm);
        }
    }
}

__global__ void h2g3_kernel(const float* __restrict__ g2, const float* __restrict__ agg2,
                            const float* __restrict__ dinv,
                            const float* __restrict__ b2, const float* __restrict__ W3,
                            float* __restrict__ g3) {
    int i = blockIdx.x * blockDim.x + threadIdx.x;
    if (i >= NN) return;
    float di = dinv[i];
    float di2 = di * di;
    float4 a = ((const float4*)agg2)[i];
    float4 g = ((const float4*)g2)[i];
    float h2[4];
    h2[0] = tanhf(a.x + g.x * di2 + b2[0]);
    h2[1] = tanhf(a.y + g.y * di2 + b2[1]);
    h2[2] = tanhf(a.z + g.z * di2 + b2[2]);
    h2[3] = tanhf(a.w + g.w * di2 + b2[3]);
    float2 o;
    o.x = h2[0]*W3[0] + h2[1]*W3[2] + h2[2]*W3[4] + h2[3]*W3[6];
    o.y = h2[0]*W3[1] + h2[1]*W3[3] + h2[2]*W3[5] + h2[3]*W3[7];
    ((float2*)g3)[i] = o;
}

__global__ void agg3_kernel(const int* __restrict__ src, const int* __restrict__ dst,
                            const float* __restrict__ g3, const float* __restrict__ dinv,
                            float* __restrict__ agg3) {
    int e = (blockIdx.x * blockDim.x + threadIdx.x) * 4;
    if (e + 3 < NE) {
        int4 s = *(const int4*)(src + e);
        int4 d = *(const int4*)(dst + e);
#pragma unroll
        for (int k = 0; k < 4; ++k) {
            int ss = (k==0)?s.x:(k==1)?s.y:(k==2)?s.z:s.w;
            int dd = (k==0)?d.x:(k==1)?d.y:(k==2)?d.z:d.w;
            float nrm = dinv[ss] * dinv[dd];
            float2 g = ((const float2*)g3)[ss];
            unsafeAtomicAdd(&agg3[dd*2+0], g.x * nrm);
            unsafeAtomicAdd(&agg3[dd*2+1], g.y * nrm);
        }
    } else {
        for (; e < NE; ++e) {
            int ss = src[e], dd = dst[e];
            float nrm = dinv[ss] * dinv[dd];
            float2 g = ((const float2*)g3)[ss];
            unsafeAtomicAdd(&agg3[dd*2+0], g.x * nrm);
            unsafeAtomicAdd(&agg3[dd*2+1], g.y * nrm);
        }
    }
}

__global__ void final_kernel(const float* __restrict__ g3, const float* __restrict__ agg3,
                             const float* __restrict__ dinv,
                             const float* __restrict__ b3,
                             const float* __restrict__ Wc, const float* __restrict__ bc,
                             float* __restrict__ out) {
    int i = blockIdx.x * blockDim.x + threadIdx.x;
    if (i >= NN) return;
    float di = dinv[i];
    float di2 = di * di;
    float2 a = ((const float2*)agg3)[i];
    float2 g = ((const float2*)g3)[i];
    float h0 = tanhf(a.x + g.x * di2 + b3[0]);
    float h1 = tanhf(a.y + g.y * di2 + b3[1]);
    out[i] = h0 * Wc[0] + h1 * Wc[1] + bc[0];
    out[NN + 2*i + 0] = h0;
    out[NN + 2*i + 1] = h1;
}

extern "C" void kernel_launch(void* const* d_in, const int* in_sizes, int n_in,
                              void* d_out, int out_size, void* d_ws, size_t ws_size,
                              hipStream_t stream) {
    const float* x   = (const float*)d_in[0];
    const int*   ei  = (const int*)d_in[1];
    const float* W1  = (const float*)d_in[2];
    const float* b1  = (const float*)d_in[3];
    const float* W2  = (const float*)d_in[4];
    const float* b2  = (const float*)d_in[5];
    const float* W3  = (const float*)d_in[6];
    const float* b3  = (const float*)d_in[7];
    const float* Wc  = (const float*)d_in[8];
    const float* bc  = (const float*)d_in[9];
    float* out = (float*)d_out;
    float* ws  = (float*)d_ws;

    const int* src = ei;
    const int* dst = ei + NE;

    float* deg  = ws;             // becomes dinv
    float* s1   = ws + (size_t)NN;
    float* g2   = ws + 2*(size_t)NN;
    float* agg2 = ws + 6*(size_t)NN;
    float* g3   = ws + 10*(size_t)NN;
    float* agg3 = ws + 12*(size_t)NN;

    const int B = 256;
    const int edge_blocks = (NE / 4 + B - 1) / B;   // 15625
    const int node_blocks = (NN + B - 1) / B;       // 1954

    hipLaunchKernelGGL(init_ws, dim3(2048), dim3(B), 0, stream, ws);
    hipLaunchKernelGGL(deg_kernel, dim3(edge_blocks), dim3(B), 0, stream, dst, deg);
    hipLaunchKernelGGL(dinv_kernel, dim3(node_blocks), dim3(B), 0, stream, deg);
    hipLaunchKernelGGL(agg1_kernel, dim3(edge_blocks), dim3(B), 0, stream, src, dst, x, deg, s1);
    hipLaunchKernelGGL(h1g2_kernel, dim3(node_blocks), dim3(B), 0, stream, x, deg, s1, W1, b1, W2, g2);
    hipLaunchKernelGGL(agg2_kernel, dim3(edge_blocks), dim3(B), 0, stream, src, dst, g2, deg, agg2);
    hipLaunchKernelGGL(h2g3_kernel, dim3(node_blocks), dim3(B), 0, stream, g2, agg2, deg, b2, W3, g3);
    hipLaunchKernelGGL(agg3_kernel, dim3(edge_blocks), dim3(B), 0, stream, src, dst, g3, deg, agg3);
    hipLaunchKernelGGL(final_kernel, dim3(node_blocks), dim3(B), 0, stream, g3, agg3, deg, b3, Wc, bc, out);
}

// Round 2
// 1402.949 us; speedup vs baseline: 4.4846x; 4.4846x over previous
//
#include <hip/hip_runtime.h>

#define NN 500000
#define NE 16000000
#define OVF_CAP 2000000

// ============================ padded-bucket path ============================
// ws layout (4B units):
// [0,NN)        cnt (int)        — edge count per dst (true count, even if >C)
// [NN,2NN)      dinv (f32)
// [2NN,3NN)     p1 = x*dinv
// [3NN,4NN)     agg1
// [4NN,8NN)     p2 = dinv*(h1@W2)   (float4)
// [8NN,12NN)    agg2                (float4)
// [12NN,14NN)   p3 = dinv*(h2@W3)   (float2)
// [14NN,16NN)   agg3                (float2)
// [16NN]        ovf_cnt (int)
// [16NN+4, 16NN+4+2*OVF_CAP)  ovf pairs (src,dst)
// [16NN+4+2*OVF_CAP, ...)     bucket (NN*C ints)

__global__ void scatter_kernel(const int* __restrict__ src, const int* __restrict__ dst,
                               int* __restrict__ cnt, int* __restrict__ bucket,
                               int* __restrict__ ovf, int* __restrict__ ovf_cnt, int C) {
    int e = (blockIdx.x * blockDim.x + threadIdx.x) * 4;
    if (e + 3 < NE) {
        int4 s4 = *(const int4*)(src + e);
        int4 d4 = *(const int4*)(dst + e);
        int ss[4] = {s4.x, s4.y, s4.z, s4.w};
        int dd[4] = {d4.x, d4.y, d4.z, d4.w};
#pragma unroll
        for (int k = 0; k < 4; ++k) {
            int pos = atomicAdd(&cnt[dd[k]], 1);
            if (pos < C) bucket[(size_t)dd[k] * C + pos] = ss[k];
            else {
                int o = atomicAdd(ovf_cnt, 1);
                if (o < OVF_CAP) { ovf[2*o] = ss[k]; ovf[2*o+1] = dd[k]; }
            }
        }
    } else {
        for (; e < NE; ++e) {
            int s = src[e], d = dst[e];
            int pos = atomicAdd(&cnt[d], 1);
            if (pos < C) bucket[(size_t)d * C + pos] = s;
            else {
                int o = atomicAdd(ovf_cnt, 1);
                if (o < OVF_CAP) { ovf[2*o] = s; ovf[2*o+1] = d; }
            }
        }
    }
}

__global__ void dinvp1_kernel(const int* __restrict__ cnt, const float* __restrict__ x,
                              float* __restrict__ dinv, float* __restrict__ p1) {
    int i = blockIdx.x * blockDim.x + threadIdx.x;
    if (i >= NN) return;
    float di = rsqrtf((float)cnt[i] + 1.0f);
    dinv[i] = di;
    p1[i] = x[i] * di;
}

template<int F>
__global__ void gather_kernel(const int* __restrict__ cnt, const int* __restrict__ bucket,
                              int C, const float* __restrict__ p, float* __restrict__ agg) {
    int i = blockIdx.x * blockDim.x + threadIdx.x;
    if (i >= NN) return;
    int n = cnt[i];
    if (n > C) n = C;
    const int* row = bucket + (size_t)i * C;
    float s[F];
#pragma unroll
    for (int f = 0; f < F; ++f) s[f] = 0.0f;
    int k = 0;
    for (; k + 3 < n; k += 4) {
        int4 id4 = *(const int4*)(row + k);
        int ids[4] = {id4.x, id4.y, id4.z, id4.w};
#pragma unroll
        for (int j = 0; j < 4; ++j) {
            if constexpr (F == 4) {
                float4 v = *(const float4*)(p + (size_t)ids[j] * 4);
                s[0] += v.x; s[1] += v.y; s[2] += v.z; s[3] += v.w;
            } else if constexpr (F == 2) {
                float2 v = *(const float2*)(p + (size_t)ids[j] * 2);
                s[0] += v.x; s[1] += v.y;
            } else {
                s[0] += p[ids[j]];
            }
        }
    }
    for (; k < n; ++k) {
        int id = row[k];
        if constexpr (F == 4) {
            float4 v = *(const float4*)(p + (size_t)id * 4);
            s[0] += v.x; s[1] += v.y; s[2] += v.z; s[3] += v.w;
        } else if constexpr (F == 2) {
            float2 v = *(const float2*)(p + (size_t)id * 2);
            s[0] += v.x; s[1] += v.y;
        } else {
            s[0] += p[id];
        }
    }
#pragma unroll
    for (int f = 0; f < F; ++f) agg[(size_t)i * F + f] = s[f];
}

template<int F>
__global__ void ovf_apply_kernel(const int* __restrict__ ovf_cnt, const int* __restrict__ ovf,
                                 const float* __restrict__ p, float* __restrict__ agg) {
    int total = *ovf_cnt;
    if (total > OVF_CAP) total = OVF_CAP;
    int stride = gridDim.x * blockDim.x;
    for (int i = blockIdx.x * blockDim.x + threadIdx.x; i < total; i += stride) {
        int ss = ovf[2*i], dd = ovf[2*i+1];
#pragma unroll
        for (int f = 0; f < F; ++f)
            unsafeAtomicAdd(&agg[(size_t)dd * F + f], p[(size_t)ss * F + f]);
    }
}

__global__ void epi1_kernel(const float* __restrict__ agg1, const float* __restrict__ x,
                            const float* __restrict__ dinv,
                            const float* __restrict__ W1, const float* __restrict__ b1,
                            const float* __restrict__ W2, float* __restrict__ p2) {
    int i = blockIdx.x * blockDim.x + threadIdx.x;
    if (i >= NN) return;
    float di = dinv[i];
    float t = di * agg1[i] + x[i] * di * di;
    float h1[4];
#pragma unroll
    for (int f = 0; f < 4; ++f) h1[f] = tanhf(t * W1[f] + b1[f]);
    float4 g;
    g.x = h1[0]*W2[0] + h1[1]*W2[4] + h1[2]*W2[8]  + h1[3]*W2[12];
    g.y = h1[0]*W2[1] + h1[1]*W2[5] + h1[2]*W2[9]  + h1[3]*W2[13];
    g.z = h1[0]*W2[2] + h1[1]*W2[6] + h1[2]*W2[10] + h1[3]*W2[14];
    g.w = h1[0]*W2[3] + h1[1]*W2[7] + h1[2]*W2[11] + h1[3]*W2[15];
    g.x *= di; g.y *= di; g.z *= di; g.w *= di;
    ((float4*)p2)[i] = g;
}

__global__ void epi2_kernel(const float* __restrict__ agg2, const float* __restrict__ p2,
                            const float* __restrict__ dinv,
                            const float* __restrict__ b2, const float* __restrict__ W3,
                            float* __restrict__ p3) {
    int i = blockIdx.x * blockDim.x + threadIdx.x;
    if (i >= NN) return;
    float di = dinv[i];
    float4 a = ((const float4*)agg2)[i];
    float4 q = ((const float4*)p2)[i];
    float h2[4];
    h2[0] = tanhf(di * a.x + q.x * di + b2[0]);
    h2[1] = tanhf(di * a.y + q.y * di + b2[1]);
    h2[2] = tanhf(di * a.z + q.z * di + b2[2]);
    h2[3] = tanhf(di * a.w + q.w * di + b2[3]);
    float2 o;
    o.x = h2[0]*W3[0] + h2[1]*W3[2] + h2[2]*W3[4] + h2[3]*W3[6];
    o.y = h2[0]*W3[1] + h2[1]*W3[3] + h2[2]*W3[5] + h2[3]*W3[7];
    o.x *= di; o.y *= di;
    ((float2*)p3)[i] = o;
}

__global__ void final2_kernel(const float* __restrict__ agg3, const float* __restrict__ p3,
                              const float* __restrict__ dinv,
                              const float* __restrict__ b3,
                              const float* __restrict__ Wc, const float* __restrict__ bc,
                              float* __restrict__ out) {
    int i = blockIdx.x * blockDim.x + threadIdx.x;
    if (i >= NN) return;
    float di = dinv[i];
    float2 a = ((const float2*)agg3)[i];
    float2 q = ((const float2*)p3)[i];
    float h0 = tanhf(di * a.x + q.x * di + b3[0]);
    float h1 = tanhf(di * a.y + q.y * di + b3[1]);
    out[i] = h0 * Wc[0] + h1 * Wc[1] + bc[0];
    out[NN + 2*i + 0] = h0;
    out[NN + 2*i + 1] = h1;
}

// ============================ v1 fallback (pure atomic, 28MB ws) ============================

__global__ void init_ws(float* __restrict__ ws) {
    long long stride = (long long)gridDim.x * blockDim.x;
    for (long long i = (long long)blockIdx.x * blockDim.x + threadIdx.x;
         i < 14LL * NN; i += stride) {
        ws[i] = (i < NN) ? 1.0f : 0.0f;
    }
}

__global__ void deg_kernel(const int* __restrict__ dst, float* __restrict__ deg) {
    int e = (blockIdx.x * blockDim.x + threadIdx.x) * 4;
    if (e + 3 < NE) {
        int4 d = *(const int4*)(dst + e);
        unsafeAtomicAdd(&deg[d.x], 1.0f);
        unsafeAtomicAdd(&deg[d.y], 1.0f);
        unsafeAtomicAdd(&deg[d.z], 1.0f);
        unsafeAtomicAdd(&deg[d.w], 1.0f);
    } else {
        for (; e < NE; ++e) unsafeAtomicAdd(&deg[dst[e]], 1.0f);
    }
}

__global__ void dinv_kernel(float* __restrict__ deg) {
    int i = blockIdx.x * blockDim.x + threadIdx.x;
    if (i < NN) deg[i] = rsqrtf(deg[i]);
}

__global__ void agg1_kernel(const int* __restrict__ src, const int* __restrict__ dst,
                            const float* __restrict__ x, const float* __restrict__ dinv,
                            float* __restrict__ s1) {
    int e = (blockIdx.x * blockDim.x + threadIdx.x) * 4;
    if (e + 3 < NE) {
        int4 s = *(const int4*)(src + e);
        int4 d = *(const int4*)(dst + e);
        unsafeAtomicAdd(&s1[d.x], x[s.x] * dinv[s.x] * dinv[d.x]);
        unsafeAtomicAdd(&s1[d.y], x[s.y] * dinv[s.y] * dinv[d.y]);
        unsafeAtomicAdd(&s1[d.z], x[s.z] * dinv[s.z] * dinv[d.z]);
        unsafeAtomicAdd(&s1[d.w], x[s.w] * dinv[s.w] * dinv[d.w]);
    } else {
        for (; e < NE; ++e)
            unsafeAtomicAdd(&s1[dst[e]], x[src[e]] * dinv[src[e]] * dinv[dst[e]]);
    }
}

__global__ void h1g2_kernel(const float* __restrict__ x, const float* __restrict__ dinv,
                            const float* __restrict__ s1,
                            const float* __restrict__ W1, const float* __restrict__ b1,
                            const float* __restrict__ W2,
                            float* __restrict__ g2) {
    int i = blockIdx.x * blockDim.x + threadIdx.x;
    if (i >= NN) return;
    float di = dinv[i];
    float t = s1[i] + x[i] * di * di;
    float h1[4];
#pragma unroll
    for (int f = 0; f < 4; ++f) h1[f] = tanhf(t * W1[f] + b1[f]);
    float4 g;
    g.x = h1[0]*W2[0] + h1[1]*W2[4] + h1[2]*W2[8]  + h1[3]*W2[12];
    g.y = h1[0]*W2[1] + h1[1]*W2[5] + h1[2]*W2[9]  + h1[3]*W2[13];
    g.z = h1[0]*W2[2] + h1[1]*W2[6] + h1[2]*W2[10] + h1[3]*W2[14];
    g.w = h1[0]*W2[3] + h1[1]*W2[7] + h1[2]*W2[11] + h1[3]*W2[15];
    ((float4*)g2)[i] = g;
}

__global__ void agg2_kernel(const int* __restrict__ src, const int* __restrict__ dst,
                            const float* __restrict__ g2, const float* __restrict__ dinv,
                            float* __restrict__ agg2) {
    int e = (blockIdx.x * blockDim.x + threadIdx.x) * 4;
    if (e + 3 < NE) {
        int4 s = *(const int4*)(src + e);
        int4 d = *(const int4*)(dst + e);
#pragma unroll
        for (int k = 0; k < 4; ++k) {
            int ss = (k==0)?s.x:(k==1)?s.y:(k==2)?s.z:s.w;
            int dd = (k==0)?d.x:(k==1)?d.y:(k==2)?d.z:d.w;
            float nrm = dinv[ss] * dinv[dd];
            float4 g = ((const float4*)g2)[ss];
            unsafeAtomicAdd(&agg2[dd*4+0], g.x * nrm);
            unsafeAtomicAdd(&agg2[dd*4+1], g.y * nrm);
            unsafeAtomicAdd(&agg2[dd*4+2], g.z * nrm);
            unsafeAtomicAdd(&agg2[dd*4+3], g.w * nrm);
        }
    } else {
        for (; e < NE; ++e) {
            int ss = src[e], dd = dst[e];
            float nrm = dinv[ss] * dinv[dd];
            float4 g = ((const float4*)g2)[ss];
            unsafeAtomicAdd(&agg2[dd*4+0], g.x * nrm);
            unsafeAtomicAdd(&agg2[dd*4+1], g.y * nrm);
            unsafeAtomicAdd(&agg2[dd*4+2], g.z * nrm);
            unsafeAtomicAdd(&agg2[dd*4+3], g.w * nrm);
        }
    }
}

__global__ void h2g3_kernel(const float* __restrict__ g2, const float* __restrict__ agg2,
                            const float* __restrict__ dinv,
                            const float* __restrict__ b2, const float* __restrict__ W3,
                            float* __restrict__ g3) {
    int i = blockIdx.x * blockDim.x + threadIdx.x;
    if (i >= NN) return;
    float di = dinv[i];
    float di2 = di * di;
    float4 a = ((const float4*)agg2)[i];
    float4 g = ((const float4*)g2)[i];
    float h2[4];
    h2[0] = tanhf(a.x + g.x * di2 + b2[0]);
    h2[1] = tanhf(a.y + g.y * di2 + b2[1]);
    h2[2] = tanhf(a.z + g.z * di2 + b2[2]);
    h2[3] = tanhf(a.w + g.w * di2 + b2[3]);
    float2 o;
    o.x = h2[0]*W3[0] + h2[1]*W3[2] + h2[2]*W3[4] + h2[3]*W3[6];
    o.y = h2[0]*W3[1] + h2[1]*W3[3] + h2[2]*W3[5] + h2[3]*W3[7];
    ((float2*)g3)[i] = o;
}

__global__ void agg3_kernel(const int* __restrict__ src, const int* __restrict__ dst,
                            const float* __restrict__ g3, const float* __restrict__ dinv,
                            float* __restrict__ agg3) {
    int e = (blockIdx.x * blockDim.x + threadIdx.x) * 4;
    if (e + 3 < NE) {
        int4 s = *(const int4*)(src + e);
        int4 d = *(const int4*)(dst + e);
#pragma unroll
        for (int k = 0; k < 4; ++k) {
            int ss = (k==0)?s.x:(k==1)?s.y:(k==2)?s.z:s.w;
            int dd = (k==0)?d.x:(k==1)?d.y:(k==2)?d.z:d.w;
            float nrm = dinv[ss] * dinv[dd];
            float2 g = ((const float2*)g3)[ss];
            unsafeAtomicAdd(&agg3[dd*2+0], g.x * nrm);
            unsafeAtomicAdd(&agg3[dd*2+1], g.y * nrm);
        }
    } else {
        for (; e < NE; ++e) {
            int ss = src[e], dd = dst[e];
            float nrm = dinv[ss] * dinv[dd];
            float2 g = ((const float2*)g3)[ss];
            unsafeAtomicAdd(&agg3[dd*2+0], g.x * nrm);
            unsafeAtomicAdd(&agg3[dd*2+1], g.y * nrm);
        }
    }
}

__global__ void final_kernel(const float* __restrict__ g3, const float* __restrict__ agg3,
                             const float* __restrict__ dinv,
                             const float* __restrict__ b3,
                             const float* __restrict__ Wc, const float* __restrict__ bc,
                             float* __restrict__ out) {
    int i = blockIdx.x * blockDim.x + threadIdx.x;
    if (i >= NN) return;
    float di = dinv[i];
    float di2 = di * di;
    float2 a = ((const float2*)agg3)[i];
    float2 g = ((const float2*)g3)[i];
    float h0 = tanhf(a.x + g.x * di2 + b3[0]);
    float h1 = tanhf(a.y + g.y * di2 + b3[1]);
    out[i] = h0 * Wc[0] + h1 * Wc[1] + bc[0];
    out[NN + 2*i + 0] = h0;
    out[NN + 2*i + 1] = h1;
}

// ============================ launch ============================

extern "C" void kernel_launch(void* const* d_in, const int* in_sizes, int n_in,
                              void* d_out, int out_size, void* d_ws, size_t ws_size,
                              hipStream_t stream) {
    const float* x   = (const float*)d_in[0];
    const int*   ei  = (const int*)d_in[1];
    const float* W1  = (const float*)d_in[2];
    const float* b1  = (const float*)d_in[3];
    const float* W2  = (const float*)d_in[4];
    const float* b2  = (const float*)d_in[5];
    const float* W3  = (const float*)d_in[6];
    const float* b3  = (const float*)d_in[7];
    const float* Wc  = (const float*)d_in[8];
    const float* bc  = (const float*)d_in[9];
    float* out = (float*)d_out;
    float* ws  = (float*)d_ws;

    const int* src = ei;
    const int* dst = ei + NE;

    const int B = 256;
    const int edge_blocks = (NE / 4 + B - 1) / B;   // 15625
    const int node_blocks = (NN + B - 1) / B;       // 1954

    // ---- choose padded-bucket capacity C that fits ws ----
    const size_t fixed_units = 16ull * NN + 4 + 2ull * OVF_CAP;  // 12,000,004
    int C = 0;
    const int cand[4] = {80, 64, 48, 32};
    for (int ci = 0; ci < 4; ++ci) {
        if (ws_size / 4 >= fixed_units + (size_t)NN * cand[ci]) { C = cand[ci]; break; }
    }

    if (C > 0) {
        int*   cnt    = (int*)ws;
        float* dinv   = ws + (size_t)NN;
        float* p1     = ws + 2ull * NN;
        float* agg1   = ws + 3ull * NN;
        float* p2     = ws + 4ull * NN;
        float* agg2   = ws + 8ull * NN;
        float* p3     = ws + 12ull * NN;
        float* agg3   = ws + 14ull * NN;
        int*   ovfcnt = (int*)(ws + 16ull * NN);
        int*   ovf    = (int*)(ws + 16ull * NN + 4);
        int*   bucket = (int*)(ws + fixed_units);

        hipMemsetAsync(cnt, 0, (size_t)NN * 4, stream);
        hipMemsetAsync(ovfcnt, 0, 4, stream);

        hipLaunchKernelGGL(scatter_kernel, dim3(edge_blocks), dim3(B), 0, stream,
                           src, dst, cnt, bucket, ovf, ovfcnt, C);
        hipLaunchKernelGGL(dinvp1_kernel, dim3(node_blocks), dim3(B), 0, stream,
                           cnt, x, dinv, p1);

        hipLaunchKernelGGL((gather_kernel<1>), dim3(node_blocks), dim3(B), 0, stream,
                           cnt, bucket, C, p1, agg1);
        hipLaunchKernelGGL((ovf_apply_kernel<1>), dim3(256), dim3(B), 0, stream,
                           ovfcnt, ovf, p1, agg1);
        hipLaunchKernelGGL(epi1_kernel, dim3(node_blocks), dim3(B), 0, stream,
                           agg1, x, dinv, W1, b1, W2, p2);

        hipLaunchKernelGGL((gather_kernel<4>), dim3(node_blocks), dim3(B), 0, stream,
                           cnt, bucket, C, p2, agg2);
        hipLaunchKernelGGL((ovf_apply_kernel<4>), dim3(256), dim3(B), 0, stream,
                           ovfcnt, ovf, p2, agg2);
        hipLaunchKernelGGL(epi2_kernel, dim3(node_blocks), dim3(B), 0, stream,
                           agg2, p2, dinv, b2, W3, p3);

        hipLaunchKernelGGL((gather_kernel<2>), dim3(node_blocks), dim3(B), 0, stream,
                           cnt, bucket, C, p3, agg3);
        hipLaunchKernelGGL((ovf_apply_kernel<2>), dim3(256), dim3(B), 0, stream,
                           ovfcnt, ovf, p3, agg3);
        hipLaunchKernelGGL(final2_kernel, dim3(node_blocks), dim3(B), 0, stream,
                           agg3, p3, dinv, b3, Wc, bc, out);
    } else {
        // -------- v1 fallback (ws too small for buckets) --------
        float* deg  = ws;
        float* s1   = ws + (size_t)NN;
        float* g2   = ws + 2*(size_t)NN;
        float* agg2 = ws + 6*(size_t)NN;
        float* g3   = ws + 10*(size_t)NN;
        float* agg3 = ws + 12*(size_t)NN;

        hipLaunchKernelGGL(init_ws, dim3(2048), dim3(B), 0, stream, ws);
        hipLaunchKernelGGL(deg_kernel, dim3(edge_blocks), dim3(B), 0, stream, dst, deg);
        hipLaunchKernelGGL(dinv_kernel, dim3(node_blocks), dim3(B), 0, stream, deg);
        hipLaunchKernelGGL(agg1_kernel, dim3(edge_blocks), dim3(B), 0, stream, src, dst, x, deg, s1);
        hipLaunchKernelGGL(h1g2_kernel, dim3(node_blocks), dim3(B), 0, stream, x, deg, s1, W1, b1, W2, g2);
        hipLaunchKernelGGL(agg2_kernel, dim3(edge_blocks), dim3(B), 0, stream, src, dst, g2, deg, agg2);
        hipLaunchKernelGGL(h2g3_kernel, dim3(node_blocks), dim3(B), 0, stream, g2, agg2, deg, b2, W3, g3);
        hipLaunchKernelGGL(agg3_kernel, dim3(edge_blocks), dim3(B), 0, stream, src, dst, g3, deg, agg3);
        hipLaunchKernelGGL(final_kernel, dim3(node_blocks), dim3(B), 0, stream, g3, agg3, deg, b3, Wc, bc, out);
    }
}

// Round 3
// 892.162 us; speedup vs baseline: 7.0522x; 1.5725x over previous
//
#include <hip/hip_runtime.h>

#define NN   500000
#define NE   16000000
#define NBIN 3907        // ceil(NN/128), bin = dst >> 7
#define NWG  1000        // partition workgroups
#define CHUNK  16000     // NE / NWG
#define CHUNK4 4000      // CHUNK / 4

// ws layout (4B units):
// [0,NN)                      dinv
// [NN,2NN)                    p1 = x*dinv
// [2NN,6NN)                   p2 = dinv*(h1@W2)   (float4/node)
// [6NN,8NN)                   p3 = dinv*(h2@W3)   (float2/node)
// [8NN, 8NN+NWG*NBIN)         wgHist (int)
// next NBIN                   binTotal (int)
// next NBIN+1                 binStart (int)
// next NE                     edgebuf (int, packed (src<<7)|dloc)

// ---- pass A: per-WG histogram over dst bins (LDS atomics only) ----
__global__ void hist_kernel(const int* __restrict__ dst, int* __restrict__ wgHist) {
    __shared__ int hist[NBIN];
    for (int i = threadIdx.x; i < NBIN; i += blockDim.x) hist[i] = 0;
    __syncthreads();
    const int4* d4 = (const int4*)(dst + blockIdx.x * CHUNK);
    for (int i = threadIdx.x; i < CHUNK4; i += blockDim.x) {
        int4 d = d4[i];
        atomicAdd(&hist[d.x >> 7], 1);
        atomicAdd(&hist[d.y >> 7], 1);
        atomicAdd(&hist[d.z >> 7], 1);
        atomicAdd(&hist[d.w >> 7], 1);
    }
    __syncthreads();
    int* row = wgHist + (size_t)blockIdx.x * NBIN;
    for (int i = threadIdx.x; i < NBIN; i += blockDim.x) row[i] = hist[i];
}

// ---- scan 1: per-bin exclusive scan across WGs (coalesced columns) ----
__global__ void scanbins_kernel(int* __restrict__ wgHist, int* __restrict__ binTotal) {
    int bin = blockIdx.x * blockDim.x + threadIdx.x;
    if (bin >= NBIN) return;
    int run = 0;
    for (int w = 0; w < NWG; ++w) {
        size_t idx = (size_t)w * NBIN + bin;
        int v = wgHist[idx];
        wgHist[idx] = run;
        run += v;
    }
    binTotal[bin] = run;
}

// ---- scan 2: exclusive scan over bins ----
__global__ void scantotal_kernel(const int* __restrict__ binTotal, int* __restrict__ binStart) {
    __shared__ int partials[1024];
    int t = threadIdx.x;
    int base = t * 4;
    int v[4]; int s = 0;
#pragma unroll
    for (int j = 0; j < 4; ++j) {
        int b = base + j;
        v[j] = (b < NBIN) ? binTotal[b] : 0;
        s += v[j];
    }
    partials[t] = s;
    __syncthreads();
    if (t == 0) {
        int run = 0;
        for (int i = 0; i < 1024; ++i) { int tmp = partials[i]; partials[i] = run; run += tmp; }
        binStart[NBIN] = run;  // == NE
    }
    __syncthreads();
    int off = partials[t];
#pragma unroll
    for (int j = 0; j < 4; ++j) {
        int b = base + j;
        if (b < NBIN) binStart[b] = off;
        off += v[j];
    }
}

// ---- pass B: reorder edges into bins (LDS cursor atomics only) ----
__global__ void reorder_kernel(const int* __restrict__ src, const int* __restrict__ dst,
                               const int* __restrict__ wgHist, const int* __restrict__ binStart,
                               int* __restrict__ edgebuf) {
    __shared__ int cur[NBIN];
    const int* row = wgHist + (size_t)blockIdx.x * NBIN;
    for (int i = threadIdx.x; i < NBIN; i += blockDim.x) cur[i] = binStart[i] + row[i];
    __syncthreads();
    const int4* s4 = (const int4*)(src + blockIdx.x * CHUNK);
    const int4* d4 = (const int4*)(dst + blockIdx.x * CHUNK);
    for (int i = threadIdx.x; i < CHUNK4; i += blockDim.x) {
        int4 s = s4[i]; int4 d = d4[i];
        int ss[4] = {s.x, s.y, s.z, s.w};
        int dd[4] = {d.x, d.y, d.z, d.w};
#pragma unroll
        for (int k = 0; k < 4; ++k) {
            int pos = atomicAdd(&cur[dd[k] >> 7], 1);
            edgebuf[pos] = (ss[k] << 7) | (dd[k] & 127);
        }
    }
}

// ---- degree + dinv + p1 (per bin, LDS counts) ----
__global__ void degp1_kernel(const int* __restrict__ binStart, const int* __restrict__ edgebuf,
                             const float* __restrict__ x,
                             float* __restrict__ dinv, float* __restrict__ p1) {
    __shared__ int cnt[128];
    int b = blockIdx.x;
    if (threadIdx.x < 128) cnt[threadIdx.x] = 0;
    __syncthreads();
    int e0 = binStart[b], e1 = binStart[b + 1];
    for (int i = e0 + threadIdx.x; i < e1; i += blockDim.x)
        atomicAdd(&cnt[edgebuf[i] & 127], 1);
    __syncthreads();
    if (threadIdx.x < 128) {
        int node = b * 128 + threadIdx.x;
        if (node < NN) {
            float di = rsqrtf((float)cnt[threadIdx.x] + 1.0f);
            dinv[node] = di;
            p1[node] = x[node] * di;
        }
    }
}

// ---- layer 1: gather p1 (scalar), epilogue -> p2 (float4) ----
__global__ void agg1_kernel(const int* __restrict__ binStart, const int* __restrict__ edgebuf,
                            const float* __restrict__ p1, const float* __restrict__ dinv,
                            const float* __restrict__ W1, const float* __restrict__ b1,
                            const float* __restrict__ W2, float* __restrict__ p2) {
    __shared__ float acc[128];
    int b = blockIdx.x;
    if (threadIdx.x < 128) acc[threadIdx.x] = 0.0f;
    __syncthreads();
    int e0 = binStart[b], e1 = binStart[b + 1];
    for (int i = e0 + threadIdx.x; i < e1; i += blockDim.x) {
        int e = edgebuf[i];
        atomicAdd(&acc[e & 127], p1[e >> 7]);
    }
    __syncthreads();
    if (threadIdx.x < 128) {
        int node = b * 128 + threadIdx.x;
        if (node < NN) {
            float di = dinv[node];
            float t = di * (acc[threadIdx.x] + p1[node]);   // norm-agg + self-loop
            float h1[4];
#pragma unroll
            for (int f = 0; f < 4; ++f) h1[f] = tanhf(t * W1[f] + b1[f]);
            float4 g;
            g.x = di * (h1[0]*W2[0] + h1[1]*W2[4] + h1[2]*W2[8]  + h1[3]*W2[12]);
            g.y = di * (h1[0]*W2[1] + h1[1]*W2[5] + h1[2]*W2[9]  + h1[3]*W2[13]);
            g.z = di * (h1[0]*W2[2] + h1[1]*W2[6] + h1[2]*W2[10] + h1[3]*W2[14]);
            g.w = di * (h1[0]*W2[3] + h1[1]*W2[7] + h1[2]*W2[11] + h1[3]*W2[15]);
            ((float4*)p2)[node] = g;
        }
    }
}

// ---- layer 2: gather p2 (float4), epilogue -> p3 (float2) ----
__global__ void agg2_kernel(const int* __restrict__ binStart, const int* __restrict__ edgebuf,
                            const float* __restrict__ p2, const float* __restrict__ dinv,
                            const float* __restrict__ b2, const float* __restrict__ W3,
                            float* __restrict__ p3) {
    __shared__ float acc[4 * 128];   // [f][dloc] to keep LDS atomics ~2-way
    int b = blockIdx.x;
    for (int i = threadIdx.x; i < 4 * 128; i += blockDim.x) acc[i] = 0.0f;
    __syncthreads();
    int e0 = binStart[b], e1 = binStart[b + 1];
    for (int i = e0 + threadIdx.x; i < e1; i += blockDim.x) {
        int e = edgebuf[i];
        int dloc = e & 127;
        float4 v = *(const float4*)(p2 + (size_t)(e >> 7) * 4);
        atomicAdd(&acc[0 * 128 + dloc], v.x);
        atomicAdd(&acc[1 * 128 + dloc], v.y);
        atomicAdd(&acc[2 * 128 + dloc], v.z);
        atomicAdd(&acc[3 * 128 + dloc], v.w);
    }
    __syncthreads();
    if (threadIdx.x < 128) {
        int node = b * 128 + threadIdx.x;
        if (node < NN) {
            float di = dinv[node];
            float4 pw = ((const float4*)p2)[node];
            float h2[4];
            h2[0] = tanhf(di * (acc[0 * 128 + threadIdx.x] + pw.x) + b2[0]);
            h2[1] = tanhf(di * (acc[1 * 128 + threadIdx.x] + pw.y) + b2[1]);
            h2[2] = tanhf(di * (acc[2 * 128 + threadIdx.x] + pw.z) + b2[2]);
            h2[3] = tanhf(di * (acc[3 * 128 + threadIdx.x] + pw.w) + b2[3]);
            float2 o;
            o.x = di * (h2[0]*W3[0] + h2[1]*W3[2] + h2[2]*W3[4] + h2[3]*W3[6]);
            o.y = di * (h2[0]*W3[1] + h2[1]*W3[3] + h2[2]*W3[5] + h2[3]*W3[7]);
            ((float2*)p3)[node] = o;
        }
    }
}

// ---- layer 3: gather p3 (float2), epilogue -> out ----
__global__ void agg3_kernel(const int* __restrict__ binStart, const int* __restrict__ edgebuf,
                            const float* __restrict__ p3, const float* __restrict__ dinv,
                            const float* __restrict__ b3,
                            const float* __restrict__ Wc, const float* __restrict__ bc,
                            float* __restrict__ out) {
    __shared__ float acc[2 * 128];
    int b = blockIdx.x;
    for (int i = threadIdx.x; i < 2 * 128; i += blockDim.x) acc[i] = 0.0f;
    __syncthreads();
    int e0 = binStart[b], e1 = binStart[b + 1];
    for (int i = e0 + threadIdx.x; i < e1; i += blockDim.x) {
        int e = edgebuf[i];
        int dloc = e & 127;
        float2 v = *(const float2*)(p3 + (size_t)(e >> 7) * 2);
        atomicAdd(&acc[0 * 128 + dloc], v.x);
        atomicAdd(&acc[1 * 128 + dloc], v.y);
    }
    __syncthreads();
    if (threadIdx.x < 128) {
        int node = b * 128 + threadIdx.x;
        if (node < NN) {
            float di = dinv[node];
            float2 pw = ((const float2*)p3)[node];
            float h0 = tanhf(di * (acc[0 * 128 + threadIdx.x] + pw.x) + b3[0]);
            float h1 = tanhf(di * (acc[1 * 128 + threadIdx.x] + pw.y) + b3[1]);
            out[node] = h0 * Wc[0] + h1 * Wc[1] + bc[0];
            out[NN + 2 * node + 0] = h0;
            out[NN + 2 * node + 1] = h1;
        }
    }
}

// ============================ launch ============================

extern "C" void kernel_launch(void* const* d_in, const int* in_sizes, int n_in,
                              void* d_out, int out_size, void* d_ws, size_t ws_size,
                              hipStream_t stream) {
    const float* x   = (const float*)d_in[0];
    const int*   ei  = (const int*)d_in[1];
    const float* W1  = (const float*)d_in[2];
    const float* b1  = (const float*)d_in[3];
    const float* W2  = (const float*)d_in[4];
    const float* b2  = (const float*)d_in[5];
    const float* W3  = (const float*)d_in[6];
    const float* b3  = (const float*)d_in[7];
    const float* Wc  = (const float*)d_in[8];
    const float* bc  = (const float*)d_in[9];
    float* out = (float*)d_out;
    float* ws  = (float*)d_ws;

    const int* src = ei;
    const int* dst = ei + NE;

    // ws carve-up (4B units); total ≈ 95.7 MB. R1 measured ws ≥ 112 MB (bucket
    // path with C=32 ran), so this always fits.
    float* dinv    = ws;
    float* p1      = ws + (size_t)NN;
    float* p2      = ws + 2ull * NN;
    float* p3      = ws + 6ull * NN;
    int* wgHist    = (int*)(ws + 8ull * NN);
    int* binTotal  = wgHist + (size_t)NWG * NBIN;
    int* binStart  = binTotal + NBIN;
    int* edgebuf   = binStart + NBIN + 1;

    const int B = 256;

    hipLaunchKernelGGL(hist_kernel, dim3(NWG), dim3(B), 0, stream, dst, wgHist);
    hipLaunchKernelGGL(scanbins_kernel, dim3((NBIN + B - 1) / B), dim3(B), 0, stream,
                       wgHist, binTotal);
    hipLaunchKernelGGL(scantotal_kernel, dim3(1), dim3(1024), 0, stream, binTotal, binStart);
    hipLaunchKernelGGL(reorder_kernel, dim3(NWG), dim3(B), 0, stream,
                       src, dst, wgHist, binStart, edgebuf);
    hipLaunchKernelGGL(degp1_kernel, dim3(NBIN), dim3(B), 0, stream,
                       binStart, edgebuf, x, dinv, p1);
    hipLaunchKernelGGL(agg1_kernel, dim3(NBIN), dim3(B), 0, stream,
                       binStart, edgebuf, p1, dinv, W1, b1, W2, p2);
    hipLaunchKernelGGL(agg2_kernel, dim3(NBIN), dim3(B), 0, stream,
                       binStart, edgebuf, p2, dinv, b2, W3, p3);
    hipLaunchKernelGGL(agg3_kernel, dim3(NBIN), dim3(B), 0, stream,
                       binStart, edgebuf, p3, dinv, b3, Wc, bc, out);
}